// Round 3
// baseline (10698.389 us; speedup 1.0000x reference)
//
#include <hip/hip_runtime.h>

typedef unsigned short u16;
typedef unsigned int   u32;
typedef unsigned long long u64;
typedef float f32x2 __attribute__((ext_vector_type(2)));

// ---------------------------------------------------------------------------
// K1: span_max + span_repr, all fp32. grid = (b,s) = 1024 blocks, 256 thr.
// out0 = cls (exact copy), out1 = span_repr (fp32) — ALSO the K2 A-matrix.
// ---------------------------------------------------------------------------
__global__ __launch_bounds__(256) void k1_span(
    const float* __restrict__ emb, const float* __restrict__ Wsp,
    const float* __restrict__ bsp,
    float* __restrict__ out0, float* __restrict__ out1) {
  __shared__ float SM[8][256];
  __shared__ float CLS[256];
  const int bid = blockIdx.x;          // b*256 + s
  const int b = bid >> 8, s = bid & 255;
  const int t = threadIdx.x;
  const float* eb = emb + (size_t)b * 65536;

  CLS[t] = eb[t];
  if (s == 0) out0[b * 256 + t] = eb[t];   // cls = exact fp32 copy

  float m = eb[s * 256 + t];
  SM[0][t] = m;
  #pragma unroll
  for (int w = 1; w < 8; ++w) {
    if (s + w < 256) m = fmaxf(m, eb[(s + w) * 256 + t]);
    SM[w][t] = m;   // -inf padding == keep previous max
  }
  __syncthreads();

  // cls contribution (span_W rows 256..511): shared by all 8 widths
  float cc = 0.f;
  for (int k = 0; k < 256; k += 4) {
    float4 cq = *(const float4*)&CLS[k];
    cc += cq.x * Wsp[(size_t)(256 + k + 0) * 256 + t];
    cc += cq.y * Wsp[(size_t)(256 + k + 1) * 256 + t];
    cc += cq.z * Wsp[(size_t)(256 + k + 2) * 256 + t];
    cc += cq.w * Wsp[(size_t)(256 + k + 3) * 256 + t];
  }
  float acc[8];
  const float base = bsp[t] + cc;
  #pragma unroll
  for (int w = 0; w < 8; ++w) acc[w] = base;

  for (int k = 0; k < 256; k += 4) {
    float w0 = Wsp[(size_t)(k + 0) * 256 + t];
    float w1 = Wsp[(size_t)(k + 1) * 256 + t];
    float w2 = Wsp[(size_t)(k + 2) * 256 + t];
    float w3 = Wsp[(size_t)(k + 3) * 256 + t];
    #pragma unroll
    for (int w = 0; w < 8; ++w) {
      float4 smq = *(const float4*)&SM[w][k];
      acc[w] += smq.x * w0; acc[w] += smq.y * w1;
      acc[w] += smq.z * w2; acc[w] += smq.w * w3;
    }
  }
  const float wm = Wsp[(size_t)512 * 256 + t];
  #pragma unroll
  for (int w = 0; w < 8; ++w) {
    size_t idx = ((size_t)w * 1024 + bid) * 256 + t;   // n = w*1024+b*256+s
    out1[idx] = acc[w] + (float)(w + 1) * wm;
  }
}

// ---------------------------------------------------------------------------
// K2: sims prefilter GEMM + fused online top-16 per row.
// grid = 256 blocks x 32 rows, 256 threads (4 waves; wave rg owns rows
// rg*8..+8; lane owns entity cols c2 and c2+64 of a 128-ent tile).
// Entity tile: fp32 -> RTZ bf16 pairs, 64 KB LDS, XOR-swizzled (prefilter
// precision only; exact fp64 re-rank happens in K3).
// Top-16 per row lives in REGISTERS: lane segment sub*16..+15 holds the 16
// sorted slots of rows (wrow0+sub) [tv0] and (wrow0+4+sub) [tv1].
// ---------------------------------------------------------------------------
__global__ __launch_bounds__(256) void k2_sims_topk(
    const float* __restrict__ span32, const float* __restrict__ ent, int ne,
    int* __restrict__ Ridx) {
  __shared__ u32 Elds[16384];   // 64 KB: 128 ents x 256 bf16
  const int t = threadIdx.x;
  const int lane = t & 63;
  const int rg = t >> 6;
  const int c2 = lane;
  const int wrow0 = blockIdx.x * 32 + rg * 8;
  const int slotrow = lane >> 4;   // 0..3: row-within-group for this lane
  const int slot = lane & 15;      // sorted position 0(best)..15

  float tv0 = -INFINITY, tv1 = -INFINITY;
  int   ti0 = 0x7FFFFFFF, ti1 = 0x7FFFFFFF;

  const float* Abase = span32 + (size_t)wrow0 * 256;
  const int sw2 = 2 * (c2 & 31);
  const int ntiles = (ne + 127) >> 7;

  for (int tile = 0; tile < ntiles; ++tile) {
    const int et = tile << 7;
    // ---- stage tile: fp32 global -> RTZ-bf16 pairs in LDS ----
    #pragma unroll 4
    for (int i = 0; i < 16; ++i) {
      int id = t + 256 * i;            // 0..4095: 8-elem chunks
      int row = id >> 5, off = id & 31;
      int e = et + row;
      uint4 a4 = make_uint4(0u,0u,0u,0u), b4 = make_uint4(0u,0u,0u,0u);
      if (e < ne) {
        const uint4* src = (const uint4*)(ent + (size_t)e * 256 + off * 8);
        a4 = src[0]; b4 = src[1];
      }
      u32 p0 = (a4.x >> 16) | (a4.y & 0xFFFF0000u);
      u32 p1 = (a4.z >> 16) | (a4.w & 0xFFFF0000u);
      u32 p2 = (b4.x >> 16) | (b4.y & 0xFFFF0000u);
      u32 p3 = (b4.z >> 16) | (b4.w & 0xFFFF0000u);
      int swr = 2 * (row & 31);
      u32* bse = Elds + row * 128;
      *(uint2*)(bse + (((off * 4)    ) ^ swr)) = make_uint2(p0, p1);
      *(uint2*)(bse + (((off * 4) + 2) ^ swr)) = make_uint2(p2, p3);
    }
    __syncthreads();

    f32x2 acc[8][2];
    #pragma unroll
    for (int i = 0; i < 8; ++i) {
      acc[i][0] = (f32x2){0.f, 0.f};
      acc[i][1] = (f32x2){0.f, 0.f};
    }
    const u32* E0 = Elds + c2 * 128;
    const u32* E1 = Elds + (c2 + 64) * 128;

    #pragma unroll 2
    for (int k = 0; k < 256; k += 4) {
      int hw = (k >> 1) ^ sw2;
      uint2 w0 = *(const uint2*)(E0 + hw);
      uint2 w1 = *(const uint2*)(E1 + hw);
      // lo: exact bf16 (<<16). hi: raw (low bits are neighbor's hi bits —
      // rel err <= 2^-8, fine for the prefilter; saves the v_and).
      f32x2 e0a, e0b, e1a, e1b;
      e0a.x = __uint_as_float(w0.x << 16); e0a.y = __uint_as_float(w0.x);
      e0b.x = __uint_as_float(w0.y << 16); e0b.y = __uint_as_float(w0.y);
      e1a.x = __uint_as_float(w1.x << 16); e1a.y = __uint_as_float(w1.x);
      e1b.x = __uint_as_float(w1.y << 16); e1b.y = __uint_as_float(w1.y);
      #pragma unroll
      for (int i = 0; i < 8; ++i) {
        float4 a = *(const float4*)(Abase + (size_t)i * 256 + k);  // uniform
        f32x2 a01; a01.x = a.x; a01.y = a.y;
        f32x2 a23; a23.x = a.z; a23.y = a.w;
        acc[i][0] += a01 * e0a; acc[i][0] += a23 * e0b;
        acc[i][1] += a01 * e1a; acc[i][1] += a23 * e1b;
      }
    }

    const int e0 = et + c2, e1 = et + c2 + 64;
    #pragma unroll
    for (int i = 0; i < 8; ++i) {
      const int sub = i & 3, segbase = sub * 16;
      const bool q1 = (i >= 4);
      float s0 = acc[i][0].x + acc[i][0].y;
      float s1 = acc[i][1].x + acc[i][1].y;
      float th  = __shfl(q1 ? tv1 : tv0, segbase + 15);
      int   thi = __shfl(q1 ? ti1 : ti0, segbase + 15);
      bool a0 = (e0 < ne) && (s0 > th || (s0 == th && e0 < thi));
      bool a1 = (e1 < ne) && (s1 > th || (s1 == th && e1 < thi));
      if (__ballot(a0 || a1) == 0ull) continue;
      for (int iter = 0; iter < 16; ++iter) {
        float lv = a0 ? s0 : -INFINITY;
        int   li = a0 ? e0 : 0x7FFFFFFF;
        if (a1 && (s1 > lv || (s1 == lv && e1 < li))) { lv = s1; li = e1; }
        #pragma unroll
        for (int off = 1; off < 64; off <<= 1) {
          float ov = __shfl_xor(lv, off);
          int   oi = __shfl_xor(li, off);
          if (ov > lv || (ov == lv && oi < li)) { lv = ov; li = oi; }
        }
        float cv = __shfl(q1 ? tv1 : tv0, segbase + 15);
        int   ci = __shfl(q1 ? ti1 : ti0, segbase + 15);
        if (!(lv > cv || (lv == cv && li < ci))) break;
        float myv = q1 ? tv1 : tv0;
        int   myi = q1 ? ti1 : ti0;
        bool inseg = (slotrow == sub);
        bool bet = inseg && (myv > lv || (myv == lv && myi < li));
        u64 bb = __ballot(bet);
        int p = (int)__popcll((bb >> segbase) & 0xFFFFull);
        float sv = __shfl_up(myv, 1);
        int   si = __shfl_up(myi, 1);
        if (inseg) {
          float nv = (slot < p) ? myv : ((slot == p) ? lv : sv);
          int   ni = (slot < p) ? myi : ((slot == p) ? li : si);
          if (q1) { tv1 = nv; ti1 = ni; } else { tv0 = nv; ti0 = ni; }
        }
        if (a0 && e0 == li) a0 = false;
        if (a1 && e1 == li) a1 = false;
        if (__ballot(a0 || a1) == 0ull) break;
      }
    }
    __syncthreads();
  }
  Ridx[(size_t)(wrow0 + slotrow) * 16 + slot]     = ti0;
  Ridx[(size_t)(wrow0 + 4 + slotrow) * 16 + slot] = ti1;
}

// ---------------------------------------------------------------------------
// K3: recompute span row fp64, exact re-rank of 16 candidates -> ordered
// top-8, then 2-layer star-GCN (fp32). grid = 8192 blocks, 256 threads.
// ---------------------------------------------------------------------------
__global__ __launch_bounds__(256) void k3_gcn(
    const float* __restrict__ emb, const float* __restrict__ Wsp,
    const float* __restrict__ bsp, const float* __restrict__ ent,
    const int* __restrict__ Ridx,
    const float* __restrict__ W1, const float* __restrict__ b1,
    const float* __restrict__ W2, const float* __restrict__ b2,
    float* __restrict__ out2, int ne) {
  __shared__ float  SMx[256];
  __shared__ float  CLS[256];
  __shared__ double SPN[256];
  __shared__ float  Xc[16][256];
  __shared__ float  Mm[8][256];
  __shared__ double dpart[16][16];
  __shared__ double dval[16];
  __shared__ int    cidx[16];
  __shared__ int    order[8];
  const int n = blockIdx.x;
  const int t = threadIdx.x;
  const int w = n >> 10, b = (n >> 8) & 3, s = n & 255;
  const float* eb = emb + (size_t)b * 65536;

  CLS[t] = eb[t];
  float m = eb[s * 256 + t];
  for (int j = 1; j <= w; ++j)
    if (s + j < 256) m = fmaxf(m, eb[(s + j) * 256 + t]);
  SMx[t] = m;
  if (t < 16) {
    int c = Ridx[(size_t)n * 16 + t];
    if ((unsigned)c >= (unsigned)ne) c = 0;   // defensive
    cidx[t] = c;
  }
  __syncthreads();

  // fp64 span value for column t (deterministic, matches fp64 numpy ref)
  double a = (double)bsp[t];
  for (int k = 0; k < 256; k += 4) {
    a += (double)SMx[k + 0] * (double)Wsp[(size_t)(k + 0) * 256 + t];
    a += (double)SMx[k + 1] * (double)Wsp[(size_t)(k + 1) * 256 + t];
    a += (double)SMx[k + 2] * (double)Wsp[(size_t)(k + 2) * 256 + t];
    a += (double)SMx[k + 3] * (double)Wsp[(size_t)(k + 3) * 256 + t];
  }
  for (int k = 0; k < 256; k += 4) {
    a += (double)CLS[k + 0] * (double)Wsp[(size_t)(256 + k + 0) * 256 + t];
    a += (double)CLS[k + 1] * (double)Wsp[(size_t)(256 + k + 1) * 256 + t];
    a += (double)CLS[k + 2] * (double)Wsp[(size_t)(256 + k + 2) * 256 + t];
    a += (double)CLS[k + 3] * (double)Wsp[(size_t)(256 + k + 3) * 256 + t];
  }
  a += (double)(w + 1) * (double)Wsp[(size_t)512 * 256 + t];
  SPN[t] = a;
  __syncthreads();

  // load 16 candidate rows (fp32); thread t: row t>>4, elems (t&15)*16..+16
  const int jr = t >> 4;
  const int kb = (t & 15) * 16;
  float x[16];
  {
    const float4* src = (const float4*)(ent + (size_t)cidx[jr] * 256 + kb);
    float4 v0 = src[0], v1 = src[1], v2 = src[2], v3 = src[3];
    x[0]=v0.x; x[1]=v0.y; x[2]=v0.z; x[3]=v0.w;
    x[4]=v1.x; x[5]=v1.y; x[6]=v1.z; x[7]=v1.w;
    x[8]=v2.x; x[9]=v2.y; x[10]=v2.z; x[11]=v2.w;
    x[12]=v3.x; x[13]=v3.y; x[14]=v3.z; x[15]=v3.w;
    #pragma unroll
    for (int q = 0; q < 16; ++q) Xc[jr][kb + q] = x[q];
  }
  double pp = 0.0;
  #pragma unroll
  for (int kk = 0; kk < 16; ++kk) pp += (double)x[kk] * SPN[kb + kk];
  dpart[jr][t & 15] = pp;
  __syncthreads();
  if (t < 16) {
    double sacc = 0.0;
    for (int q = 0; q < 16; ++q) sacc += dpart[t][q];   // fixed order
    dval[t] = sacc;
  }
  __syncthreads();
  if (t == 0) {   // exact ordered top-8 of 16 (val desc, idx asc on ties)
    unsigned used = 0;
    for (int o = 0; o < 8; ++o) {
      int best = -1; double bv = 0.0; int bi = 0;
      for (int j = 0; j < 16; ++j) {
        if (used & (1u << j)) continue;
        if (best < 0 || dval[j] > bv || (dval[j] == bv && cidx[j] < bi)) {
          best = j; bv = dval[j]; bi = cidx[j];
        }
      }
      used |= (1u << best);
      order[o] = best;
    }
  }
  __syncthreads();

  // M = A_norm @ X (star: center 1/8 & 1/4; satellites 1/4 & 1/2)
  {
    float x0 = Xc[order[0]][t];
    float xs[7]; float ssum = 0.f;
    #pragma unroll
    for (int j = 1; j < 8; ++j) { xs[j - 1] = Xc[order[j]][t]; ssum += xs[j - 1]; }
    Mm[0][t] = x0 * 0.125f + ssum * 0.25f;
    #pragma unroll
    for (int j = 1; j < 8; ++j) Mm[j][t] = x0 * 0.25f + xs[j - 1] * 0.5f;
  }
  __syncthreads();

  // layer 1: Y = relu(M @ W1 + b1)
  float acc[8];
  {
    float bbv = b1[t];
    #pragma unroll
    for (int r = 0; r < 8; ++r) acc[r] = bbv;
    for (int k = 0; k < 256; k += 4) {
      float w0 = W1[(size_t)(k + 0) * 256 + t];
      float w1 = W1[(size_t)(k + 1) * 256 + t];
      float w2 = W1[(size_t)(k + 2) * 256 + t];
      float w3 = W1[(size_t)(k + 3) * 256 + t];
      #pragma unroll
      for (int r = 0; r < 8; ++r) {
        float4 mq = *(const float4*)&Mm[r][k];
        acc[r] += mq.x * w0; acc[r] += mq.y * w1;
        acc[r] += mq.z * w2; acc[r] += mq.w * w3;
      }
    }
  }
  #pragma unroll
  for (int r = 0; r < 8; ++r) Xc[r][t] = fmaxf(acc[r], 0.f);
  __syncthreads();

  // M2 = A_norm @ Y
  {
    float y0 = Xc[0][t];
    float ys[7]; float ss = 0.f;
    #pragma unroll
    for (int j = 1; j < 8; ++j) { ys[j - 1] = Xc[j][t]; ss += ys[j - 1]; }
    float m0 = y0 * 0.125f + ss * 0.25f;
    float mj[7];
    #pragma unroll
    for (int j = 1; j < 8; ++j) mj[j - 1] = y0 * 0.25f + ys[j - 1] * 0.5f;
    Mm[0][t] = m0;
    #pragma unroll
    for (int j = 1; j < 8; ++j) Mm[j][t] = mj[j - 1];
  }
  __syncthreads();

  // layer 2: out = M2 @ W2 + b2
  {
    float bbv = b2[t];
    #pragma unroll
    for (int r = 0; r < 8; ++r) acc[r] = bbv;
    for (int k = 0; k < 256; k += 4) {
      float w0 = W2[(size_t)(k + 0) * 256 + t];
      float w1 = W2[(size_t)(k + 1) * 256 + t];
      float w2 = W2[(size_t)(k + 2) * 256 + t];
      float w3 = W2[(size_t)(k + 3) * 256 + t];
      #pragma unroll
      for (int r = 0; r < 8; ++r) {
        float4 mq = *(const float4*)&Mm[r][k];
        acc[r] += mq.x * w0; acc[r] += mq.y * w1;
        acc[r] += mq.z * w2; acc[r] += mq.w * w3;
      }
    }
  }
  float* ob = out2 + (size_t)n * 2048 + t;
  #pragma unroll
  for (int r = 0; r < 8; ++r) ob[(size_t)r * 256] = acc[r];
}

// ---------------------------------------------------------------------------
extern "C" void kernel_launch(void* const* d_in, const int* in_sizes, int n_in,
                              void* d_out, int out_size, void* d_ws, size_t ws_size,
                              hipStream_t stream) {
  const float* emb = (const float*)d_in[0];
  const float* ent = (const float*)d_in[1];
  const float* Wsp = (const float*)d_in[2];
  const float* bsp = (const float*)d_in[3];
  const float* W1  = (const float*)d_in[4];
  const float* b1  = (const float*)d_in[5];
  const float* W2  = (const float*)d_in[6];
  const float* b2  = (const float*)d_in[7];
  const int ne = in_sizes[1] / 256;   // 50000

  float* out  = (float*)d_out;
  float* out0 = out;                        // cls: 1024
  float* out1 = out + 1024;                 // span_repr: 8192*256 (K2's A)
  float* out2 = out + 1024 + 2097152;       // subgraph_out: 8192*8*256
  int* Ridx = (int*)d_ws;                   // 512 KB — only ws use

  hipLaunchKernelGGL(k1_span, dim3(1024), dim3(256), 0, stream,
                     emb, Wsp, bsp, out0, out1);
  hipLaunchKernelGGL(k2_sims_topk, dim3(256), dim3(256), 0, stream,
                     out1, ent, ne, Ridx);
  hipLaunchKernelGGL(k3_gcn, dim3(8192), dim3(256), 0, stream,
                     emb, Wsp, bsp, ent, Ridx, W1, b1, W2, b2, out2, ne);
}

// Round 4
// 3483.721 us; speedup vs baseline: 3.0710x; 3.0710x over previous
//
#include <hip/hip_runtime.h>

typedef unsigned short u16;
typedef unsigned int   u32;
typedef unsigned long long u64;
typedef short bf16x8 __attribute__((ext_vector_type(8)));
typedef float f32x4  __attribute__((ext_vector_type(4)));

#define INF_F __builtin_inff()

__device__ __forceinline__ u16 f2bf(float f) {
  u32 u = __float_as_uint(f);
  return (u16)((u + 0x7FFFu + ((u >> 16) & 1u)) >> 16);   // RNE
}

// ---------------------------------------------------------------------------
// K0: entity table fp32 -> bf16 (RNE), row-major [ne][256]. n4 = ne*64.
// ---------------------------------------------------------------------------
__global__ __launch_bounds__(256) void k0_cvt(
    const float* __restrict__ src, u16* __restrict__ dst, int n4) {
  int id = blockIdx.x * 256 + threadIdx.x;
  if (id >= n4) return;
  float4 v = ((const float4*)src)[id];
  ((ushort4*)dst)[id] = make_ushort4(f2bf(v.x), f2bf(v.y), f2bf(v.z), f2bf(v.w));
}

// ---------------------------------------------------------------------------
// K1: span_max + span_repr fp32 (+ bf16 copy for MFMA prefilter).
// grid = 1024 blocks (b,s), 256 threads.
// ---------------------------------------------------------------------------
__global__ __launch_bounds__(256) void k1_span(
    const float* __restrict__ emb, const float* __restrict__ Wsp,
    const float* __restrict__ bsp,
    float* __restrict__ out0, float* __restrict__ out1,
    u16* __restrict__ spanbf) {
  __shared__ float SM[8][256];
  __shared__ float CLS[256];
  const int bid = blockIdx.x;          // b*256 + s
  const int b = bid >> 8, s = bid & 255;
  const int t = threadIdx.x;
  const float* eb = emb + (size_t)b * 65536;

  CLS[t] = eb[t];
  if (s == 0) out0[b * 256 + t] = eb[t];

  float m = eb[s * 256 + t];
  SM[0][t] = m;
  #pragma unroll
  for (int w = 1; w < 8; ++w) {
    if (s + w < 256) m = fmaxf(m, eb[(s + w) * 256 + t]);
    SM[w][t] = m;
  }
  __syncthreads();

  float cc = 0.f;
  for (int k = 0; k < 256; k += 4) {
    float4 cq = *(const float4*)&CLS[k];
    cc += cq.x * Wsp[(size_t)(256 + k + 0) * 256 + t];
    cc += cq.y * Wsp[(size_t)(256 + k + 1) * 256 + t];
    cc += cq.z * Wsp[(size_t)(256 + k + 2) * 256 + t];
    cc += cq.w * Wsp[(size_t)(256 + k + 3) * 256 + t];
  }
  float acc[8];
  const float base = bsp[t] + cc;
  #pragma unroll
  for (int w = 0; w < 8; ++w) acc[w] = base;

  for (int k = 0; k < 256; k += 4) {
    float w0 = Wsp[(size_t)(k + 0) * 256 + t];
    float w1 = Wsp[(size_t)(k + 1) * 256 + t];
    float w2 = Wsp[(size_t)(k + 2) * 256 + t];
    float w3 = Wsp[(size_t)(k + 3) * 256 + t];
    #pragma unroll
    for (int w = 0; w < 8; ++w) {
      float4 smq = *(const float4*)&SM[w][k];
      acc[w] += smq.x * w0; acc[w] += smq.y * w1;
      acc[w] += smq.z * w2; acc[w] += smq.w * w3;
    }
  }
  const float wm = Wsp[(size_t)512 * 256 + t];
  #pragma unroll
  for (int w = 0; w < 8; ++w) {
    float val = acc[w] + (float)(w + 1) * wm;
    size_t idx = ((size_t)w * 1024 + bid) * 256 + t;
    out1[idx] = val;
    spanbf[idx] = f2bf(val);
  }
}

// ---------------------------------------------------------------------------
// K2: bf16 MFMA sims prefilter + fused per-row top-16 (unordered, replace-min).
// grid = 512 = 64 rowgroups(128 rows) x 8 entity partitions (6250 each).
// 4 waves/block; wave wv owns rows [rg*128+wv*32, +32) as 2 A-fragments
// resident in registers. 64-ent tile staged bf16 in LDS (16B-chunk XOR
// swizzle). mfma_f32_16x16x32_bf16: A[m=lane&15][k=quad*8+j],
// B[k=quad*8+j][n=lane&15], C row=quad*4+reg, col=lane&15 (m89/m120).
// ---------------------------------------------------------------------------
__global__ __launch_bounds__(256) void k2_mfma(
    const u16* __restrict__ spanbf, const u16* __restrict__ entbf, int ne,
    float* __restrict__ Rpv, int* __restrict__ Rpi) {
  __shared__ u32   Elds[8192];        // 32 KB: 64 ents x 256 bf16, swizzled
  __shared__ float Sval[4][32][16];   // per-wave per-row 16 slots (unordered)
  __shared__ int   Sidx[4][32][16];
  __shared__ int   Aux[4][32];        // current min-slot per row
  const int t = threadIdx.x, lane = t & 63, wv = t >> 6;
  const int m = lane & 15, q = lane >> 4;
  const int rg = blockIdx.x & 63, p = blockIdx.x >> 6;
  const int psz = (ne + 7) >> 3;
  const int e_start = p * psz;
  const int e_end = min(ne, e_start + psz);
  const int rowbase = rg * 128 + wv * 32;

  #pragma unroll
  for (int j = 0; j < 8; ++j) {
    int idx = lane + 64 * j; int rw = idx >> 4, sl = idx & 15;
    Sval[wv][rw][sl] = -INF_F; Sidx[wv][rw][sl] = 0x7FFFFFFF;
  }
  if (lane < 32) Aux[wv][lane] = 0;

  // A fragments resident in registers: 2 rowfrags x 8 ksteps x 8 bf16
  bf16x8 a0[8], a1[8];
  #pragma unroll
  for (int s = 0; s < 8; ++s) {
    a0[s] = *(const bf16x8*)(spanbf + (size_t)(rowbase + m) * 256 + s * 32 + q * 8);
    a1[s] = *(const bf16x8*)(spanbf + (size_t)(rowbase + 16 + m) * 256 + s * 32 + q * 8);
  }

  float th0[4], th1[4]; int thi0[4], thi1[4];
  #pragma unroll
  for (int r = 0; r < 4; ++r) {
    th0[r] = -INF_F; th1[r] = -INF_F;
    thi0[r] = 0x7FFFFFFF; thi1[r] = 0x7FFFFFFF;
  }

  const int ntiles = (e_end - e_start + 63) >> 6;
  for (int tile = 0; tile < ntiles; ++tile) {
    const int eb = e_start + (tile << 6);
    __syncthreads();
    #pragma unroll
    for (int i = 0; i < 8; ++i) {
      int id = t + 256 * i; int e = id >> 5, qq = id & 31;
      uint4 v = make_uint4(0u, 0u, 0u, 0u);
      int ge = eb + e;
      if (ge < e_end) v = *(const uint4*)((const char*)entbf + (size_t)ge * 512 + qq * 16);
      *(uint4*)((char*)Elds + (((e << 5) | (qq ^ (e & 31))) << 4)) = v;
    }
    __syncthreads();

    for (int c = 0; c < 4; ++c) {
      f32x4 acc0 = {0.f, 0.f, 0.f, 0.f}, acc1 = {0.f, 0.f, 0.f, 0.f};
      const int el = c * 16 + m, sw = el & 31, bc = el << 5;
      #pragma unroll
      for (int s = 0; s < 8; ++s) {
        int qq = s * 4 + q;
        bf16x8 bfr = *(const bf16x8*)((const char*)Elds + (((bc | (qq ^ sw))) << 4));
        acc0 = __builtin_amdgcn_mfma_f32_16x16x32_bf16(a0[s], bfr, acc0, 0, 0, 0);
        acc1 = __builtin_amdgcn_mfma_f32_16x16x32_bf16(a1[s], bfr, acc1, 0, 0, 0);
      }
      const int gent = eb + c * 16 + m;
      const bool valid = gent < e_end;
      const u64 gm = 0xFFFFull << (q * 16);

      auto topk = [&](const f32x4& av, float* th, int* thi, int rwoff) {
        #pragma unroll
        for (int reg = 0; reg < 4; ++reg) {
          float v = av[reg];
          const int rw = rwoff + q * 4 + reg;
          bool p_ = valid && (v > th[reg] || (v == th[reg] && gent < thi[reg]));
          while (__ballot(p_) & gm) {     // quad-group parallel insert loop
            float lv = p_ ? v : -INF_F; int li = p_ ? gent : 0x7FFFFFFF;
            #pragma unroll
            for (int off = 1; off < 16; off <<= 1) {
              float ov = __shfl_xor(lv, off); int oi = __shfl_xor(li, off);
              if (ov > lv || (ov == lv && oi < li)) { lv = ov; li = oi; }
            }
            if (!(lv > th[reg] || (lv == th[reg] && li < thi[reg]))) break;
            int ms = Aux[wv][rw];
            if (m == ms) { Sval[wv][rw][ms] = lv; Sidx[wv][rw][ms] = li; }
            if (p_ && gent == li) p_ = false;
            // recompute row min (evict target) + refresh cached threshold
            float mv = Sval[wv][rw][m]; int mi = Sidx[wv][rw][m]; int msl = m;
            #pragma unroll
            for (int off = 1; off < 16; off <<= 1) {
              float ov = __shfl_xor(mv, off); int oi = __shfl_xor(mi, off);
              int os = __shfl_xor(msl, off);
              if (ov < mv || (ov == mv && oi > mi)) { mv = ov; mi = oi; msl = os; }
            }
            th[reg] = mv; thi[reg] = mi;
            if (m == 0) Aux[wv][rw] = msl;
            if (p_ && !(v > mv || (v == mv && gent < mi))) p_ = false;
          }
        }
      };
      topk(acc0, th0, thi0, 0);
      topk(acc1, th1, thi1, 16);
    }
  }

  #pragma unroll
  for (int j = 0; j < 8; ++j) {
    int idx = lane + 64 * j; int rw = idx >> 4, sl = idx & 15;
    int row = rowbase + rw;
    Rpv[(size_t)row * 128 + p * 16 + sl] = Sval[wv][rw][sl];
    Rpi[(size_t)row * 128 + p * 16 + sl] = Sidx[wv][rw][sl];
  }
}

// ---------------------------------------------------------------------------
// K2b: exact top-16 of the 128 partition candidates per row (rank counting).
// grid = 2048 blocks x 4 waves (1 row/wave).
// ---------------------------------------------------------------------------
__global__ __launch_bounds__(256) void k2_merge(
    const float* __restrict__ Rpv, const int* __restrict__ Rpi,
    int* __restrict__ Ridx) {
  const int t = threadIdx.x, lane = t & 63, wv = t >> 6;
  const int row = blockIdx.x * 4 + wv;
  const float va = Rpv[(size_t)row * 128 + lane];
  const int   ea = Rpi[(size_t)row * 128 + lane];
  const float vb = Rpv[(size_t)row * 128 + 64 + lane];
  const int   eb = Rpi[(size_t)row * 128 + 64 + lane];
  int ca = 0, cb = 0;
  for (int i = 0; i < 64; ++i) {
    float ov = __shfl(va, i); int oi = __shfl(ea, i);
    ca += (ov > va || (ov == va && oi < ea));
    cb += (ov > vb || (ov == vb && oi < eb));
  }
  for (int i = 0; i < 64; ++i) {
    float ov = __shfl(vb, i); int oi = __shfl(eb, i);
    ca += (ov > va || (ov == va && oi < ea));
    cb += (ov > vb || (ov == vb && oi < eb));
  }
  if (ca < 16) Ridx[(size_t)row * 16 + ca] = ea;
  if (cb < 16) Ridx[(size_t)row * 16 + cb] = eb;
}

// ---------------------------------------------------------------------------
// K3: recompute span row fp64, exact re-rank of 16 candidates -> ordered
// top-8, then 2-layer star-GCN (fp32). grid = 8192 blocks, 256 threads.
// ---------------------------------------------------------------------------
__global__ __launch_bounds__(256) void k3_gcn(
    const float* __restrict__ emb, const float* __restrict__ Wsp,
    const float* __restrict__ bsp, const float* __restrict__ ent,
    const int* __restrict__ Ridx,
    const float* __restrict__ W1, const float* __restrict__ b1,
    const float* __restrict__ W2, const float* __restrict__ b2,
    float* __restrict__ out2, int ne) {
  __shared__ float  SMx[256];
  __shared__ float  CLS[256];
  __shared__ double SPN[256];
  __shared__ float  Xc[16][256];
  __shared__ float  Mm[8][256];
  __shared__ double dpart[16][16];
  __shared__ double dval[16];
  __shared__ int    cidx[16];
  __shared__ int    order[8];
  const int n = blockIdx.x;
  const int t = threadIdx.x;
  const int w = n >> 10, b = (n >> 8) & 3, s = n & 255;
  const float* eb = emb + (size_t)b * 65536;

  CLS[t] = eb[t];
  float m = eb[s * 256 + t];
  for (int j = 1; j <= w; ++j)
    if (s + j < 256) m = fmaxf(m, eb[(s + j) * 256 + t]);
  SMx[t] = m;
  if (t < 16) {
    int c = Ridx[(size_t)n * 16 + t];
    if ((unsigned)c >= (unsigned)ne) c = 0;   // defensive
    cidx[t] = c;
  }
  __syncthreads();

  double a = (double)bsp[t];
  for (int k = 0; k < 256; k += 4) {
    a += (double)SMx[k + 0] * (double)Wsp[(size_t)(k + 0) * 256 + t];
    a += (double)SMx[k + 1] * (double)Wsp[(size_t)(k + 1) * 256 + t];
    a += (double)SMx[k + 2] * (double)Wsp[(size_t)(k + 2) * 256 + t];
    a += (double)SMx[k + 3] * (double)Wsp[(size_t)(k + 3) * 256 + t];
  }
  for (int k = 0; k < 256; k += 4) {
    a += (double)CLS[k + 0] * (double)Wsp[(size_t)(256 + k + 0) * 256 + t];
    a += (double)CLS[k + 1] * (double)Wsp[(size_t)(256 + k + 1) * 256 + t];
    a += (double)CLS[k + 2] * (double)Wsp[(size_t)(256 + k + 2) * 256 + t];
    a += (double)CLS[k + 3] * (double)Wsp[(size_t)(256 + k + 3) * 256 + t];
  }
  a += (double)(w + 1) * (double)Wsp[(size_t)512 * 256 + t];
  SPN[t] = a;
  __syncthreads();

  const int jr = t >> 4;
  const int kb = (t & 15) * 16;
  float x[16];
  {
    const float4* src = (const float4*)(ent + (size_t)cidx[jr] * 256 + kb);
    float4 v0 = src[0], v1 = src[1], v2 = src[2], v3 = src[3];
    x[0]=v0.x; x[1]=v0.y; x[2]=v0.z; x[3]=v0.w;
    x[4]=v1.x; x[5]=v1.y; x[6]=v1.z; x[7]=v1.w;
    x[8]=v2.x; x[9]=v2.y; x[10]=v2.z; x[11]=v2.w;
    x[12]=v3.x; x[13]=v3.y; x[14]=v3.z; x[15]=v3.w;
    #pragma unroll
    for (int qq = 0; qq < 16; ++qq) Xc[jr][kb + qq] = x[qq];
  }
  double pp = 0.0;
  #pragma unroll
  for (int kk = 0; kk < 16; ++kk) pp += (double)x[kk] * SPN[kb + kk];
  dpart[jr][t & 15] = pp;
  __syncthreads();
  if (t < 16) {
    double sacc = 0.0;
    for (int qq = 0; qq < 16; ++qq) sacc += dpart[t][qq];
    dval[t] = sacc;
  }
  __syncthreads();
  if (t == 0) {
    unsigned used = 0;
    for (int o = 0; o < 8; ++o) {
      int best = -1; double bv = 0.0; int bi = 0;
      for (int j = 0; j < 16; ++j) {
        if (used & (1u << j)) continue;
        if (best < 0 || dval[j] > bv || (dval[j] == bv && cidx[j] < bi)) {
          best = j; bv = dval[j]; bi = cidx[j];
        }
      }
      used |= (1u << best);
      order[o] = best;
    }
  }
  __syncthreads();

  {
    float x0 = Xc[order[0]][t];
    float xs[7]; float ssum = 0.f;
    #pragma unroll
    for (int j = 1; j < 8; ++j) { xs[j - 1] = Xc[order[j]][t]; ssum += xs[j - 1]; }
    Mm[0][t] = x0 * 0.125f + ssum * 0.25f;
    #pragma unroll
    for (int j = 1; j < 8; ++j) Mm[j][t] = x0 * 0.25f + xs[j - 1] * 0.5f;
  }
  __syncthreads();

  float acc[8];
  {
    float bbv = b1[t];
    #pragma unroll
    for (int r = 0; r < 8; ++r) acc[r] = bbv;
    for (int k = 0; k < 256; k += 4) {
      float w0 = W1[(size_t)(k + 0) * 256 + t];
      float w1 = W1[(size_t)(k + 1) * 256 + t];
      float w2 = W1[(size_t)(k + 2) * 256 + t];
      float w3 = W1[(size_t)(k + 3) * 256 + t];
      #pragma unroll
      for (int r = 0; r < 8; ++r) {
        float4 mq = *(const float4*)&Mm[r][k];
        acc[r] += mq.x * w0; acc[r] += mq.y * w1;
        acc[r] += mq.z * w2; acc[r] += mq.w * w3;
      }
    }
  }
  #pragma unroll
  for (int r = 0; r < 8; ++r) Xc[r][t] = fmaxf(acc[r], 0.f);
  __syncthreads();

  {
    float y0 = Xc[0][t];
    float ys[7]; float ss = 0.f;
    #pragma unroll
    for (int j = 1; j < 8; ++j) { ys[j - 1] = Xc[j][t]; ss += ys[j - 1]; }
    float m0 = y0 * 0.125f + ss * 0.25f;
    float mj[7];
    #pragma unroll
    for (int j = 1; j < 8; ++j) mj[j - 1] = y0 * 0.25f + ys[j - 1] * 0.5f;
    Mm[0][t] = m0;
    #pragma unroll
    for (int j = 1; j < 8; ++j) Mm[j][t] = mj[j - 1];
  }
  __syncthreads();

  {
    float bbv = b2[t];
    #pragma unroll
    for (int r = 0; r < 8; ++r) acc[r] = bbv;
    for (int k = 0; k < 256; k += 4) {
      float w0 = W2[(size_t)(k + 0) * 256 + t];
      float w1 = W2[(size_t)(k + 1) * 256 + t];
      float w2 = W2[(size_t)(k + 2) * 256 + t];
      float w3 = W2[(size_t)(k + 3) * 256 + t];
      #pragma unroll
      for (int r = 0; r < 8; ++r) {
        float4 mq = *(const float4*)&Mm[r][k];
        acc[r] += mq.x * w0; acc[r] += mq.y * w1;
        acc[r] += mq.z * w2; acc[r] += mq.w * w3;
      }
    }
  }
  float* ob = out2 + (size_t)n * 2048 + t;
  #pragma unroll
  for (int r = 0; r < 8; ++r) ob[(size_t)r * 256] = acc[r];
}

// ---------------------------------------------------------------------------
extern "C" void kernel_launch(void* const* d_in, const int* in_sizes, int n_in,
                              void* d_out, int out_size, void* d_ws, size_t ws_size,
                              hipStream_t stream) {
  const float* emb = (const float*)d_in[0];
  const float* ent = (const float*)d_in[1];
  const float* Wsp = (const float*)d_in[2];
  const float* bsp = (const float*)d_in[3];
  const float* W1  = (const float*)d_in[4];
  const float* b1  = (const float*)d_in[5];
  const float* W2  = (const float*)d_in[6];
  const float* b2  = (const float*)d_in[7];
  const int ne = in_sizes[1] / 256;   // 50000

  float* out  = (float*)d_out;
  float* out0 = out;                        // cls: 1024
  float* out1 = out + 1024;                 // span_repr: 8192*256
  float* out2 = out + 1024 + 2097152;       // subgraph_out: 64 MB region

  // scratch overlays on out2 (consumed before k3 overwrites; strict order):
  char* ov = (char*)out2;
  u16*   entbf  = (u16*)(ov);                     // 25.6 MB bf16 entity table
  u16*   spanbf = (u16*)(ov + 33554432);          //  4 MB bf16 span matrix
  float* Rpv    = (float*)(ov + 41943040);        //  4 MB partial topk vals
  int*   Rpi    = (int*)  (ov + 50331648);        //  4 MB partial topk idx
  int*   Ridx   = (int*)d_ws;                     // 512 KB final top-16 idx

  hipLaunchKernelGGL(k0_cvt, dim3((ne * 64 + 255) / 256), dim3(256), 0, stream,
                     ent, entbf, ne * 64);
  hipLaunchKernelGGL(k1_span, dim3(1024), dim3(256), 0, stream,
                     emb, Wsp, bsp, out0, out1, spanbf);
  hipLaunchKernelGGL(k2_mfma, dim3(512), dim3(256), 0, stream,
                     spanbf, entbf, ne, Rpv, Rpi);
  hipLaunchKernelGGL(k2_merge, dim3(2048), dim3(256), 0, stream,
                     Rpv, Rpi, Ridx);
  hipLaunchKernelGGL(k3_gcn, dim3(8192), dim3(256), 0, stream,
                     emb, Wsp, bsp, ent, Ridx, W1, b1, W2, b2, out2, ne);
}

// Round 5
// 1398.898 us; speedup vs baseline: 7.6477x; 2.4903x over previous
//
#include <hip/hip_runtime.h>

typedef unsigned short u16;
typedef unsigned int   u32;
typedef unsigned long long u64;
typedef short bf16x8 __attribute__((ext_vector_type(8)));
typedef float f32x4  __attribute__((ext_vector_type(4)));

#define INF_F __builtin_inff()

__device__ __forceinline__ u16 f2bf(float f) {
  u32 u = __float_as_uint(f);
  return (u16)((u + 0x7FFFu + ((u >> 16) & 1u)) >> 16);   // RNE
}

// ---------------------------------------------------------------------------
// K0: entity table fp32 -> bf16 (RNE), row-major [ne][256]. n4 = ne*64.
// ---------------------------------------------------------------------------
__global__ __launch_bounds__(256) void k0_cvt(
    const float* __restrict__ src, u16* __restrict__ dst, int n4) {
  int id = blockIdx.x * 256 + threadIdx.x;
  if (id >= n4) return;
  float4 v = ((const float4*)src)[id];
  ((ushort4*)dst)[id] = make_ushort4(f2bf(v.x), f2bf(v.y), f2bf(v.z), f2bf(v.w));
}

// ---------------------------------------------------------------------------
// K1: span_max + span_repr fp32 (+ bf16 copy for MFMA prefilter).
// grid = 1024 blocks (b,s), 256 threads.
// ---------------------------------------------------------------------------
__global__ __launch_bounds__(256) void k1_span(
    const float* __restrict__ emb, const float* __restrict__ Wsp,
    const float* __restrict__ bsp,
    float* __restrict__ out0, float* __restrict__ out1,
    u16* __restrict__ spanbf) {
  __shared__ float SM[8][256];
  __shared__ float CLS[256];
  const int bid = blockIdx.x;          // b*256 + s
  const int b = bid >> 8, s = bid & 255;
  const int t = threadIdx.x;
  const float* eb = emb + (size_t)b * 65536;

  CLS[t] = eb[t];
  if (s == 0) out0[b * 256 + t] = eb[t];

  float m = eb[s * 256 + t];
  SM[0][t] = m;
  #pragma unroll
  for (int w = 1; w < 8; ++w) {
    if (s + w < 256) m = fmaxf(m, eb[(s + w) * 256 + t]);
    SM[w][t] = m;
  }
  __syncthreads();

  float cc = 0.f;
  for (int k = 0; k < 256; k += 4) {
    float4 cq = *(const float4*)&CLS[k];
    cc += cq.x * Wsp[(size_t)(256 + k + 0) * 256 + t];
    cc += cq.y * Wsp[(size_t)(256 + k + 1) * 256 + t];
    cc += cq.z * Wsp[(size_t)(256 + k + 2) * 256 + t];
    cc += cq.w * Wsp[(size_t)(256 + k + 3) * 256 + t];
  }
  float acc[8];
  const float base = bsp[t] + cc;
  #pragma unroll
  for (int w = 0; w < 8; ++w) acc[w] = base;

  for (int k = 0; k < 256; k += 4) {
    float w0 = Wsp[(size_t)(k + 0) * 256 + t];
    float w1 = Wsp[(size_t)(k + 1) * 256 + t];
    float w2 = Wsp[(size_t)(k + 2) * 256 + t];
    float w3 = Wsp[(size_t)(k + 3) * 256 + t];
    #pragma unroll
    for (int w = 0; w < 8; ++w) {
      float4 smq = *(const float4*)&SM[w][k];
      acc[w] += smq.x * w0; acc[w] += smq.y * w1;
      acc[w] += smq.z * w2; acc[w] += smq.w * w3;
    }
  }
  const float wm = Wsp[(size_t)512 * 256 + t];
  #pragma unroll
  for (int w = 0; w < 8; ++w) {
    float val = acc[w] + (float)(w + 1) * wm;
    size_t idx = ((size_t)w * 1024 + bid) * 256 + t;
    out1[idx] = val;
    spanbf[idx] = f2bf(val);
  }
}

// ---------------------------------------------------------------------------
// K2: bf16 MFMA sims prefilter + per-row top-16 via lane-parallel queues.
// grid = 512 = 64 rowgroups(128 rows) x 8 entity partitions (6250 each).
// 4 waves/block; wave wv owns rows [rg*128+wv*32, +32) as 2 resident
// A-fragment sets. 64-ent tiles staged bf16 in LDS (16B-chunk XOR swizzle).
// Producers: cached-threshold compare + ballot-prefix queue append (no
// atomics). Owner lane i (i<16) drains rows {i, 16+i}: lane-local replace-min
// into unordered 16-slot LDS state. Exactness restored by K3 fp64 re-rank.
// ---------------------------------------------------------------------------
__global__ __launch_bounds__(256) void k2_mfma(
    const u16* __restrict__ spanbf, const u16* __restrict__ entbf, int ne,
    float* __restrict__ Rpv, int* __restrict__ Rpi) {
  __shared__ u32 Elds[8192];       // 32 KB: 64 ents x 256 bf16, swizzled
  __shared__ u64 Slot[4][32][16];  // 16 KB: per-wave per-row 16 slots
  __shared__ u64 Q[4][16][16];     //  8 KB: per-half-row append queue
  __shared__ u32 Qn[4][16];
  __shared__ float Sth[4][32];     // row threshold (current slot-min)
  const int t = threadIdx.x, lane = t & 63, wv = t >> 6;
  const int m = lane & 15, q = lane >> 4, q4 = q * 4;
  const int rg = blockIdx.x & 63, p = blockIdx.x >> 6;
  const int psz = (ne + 7) >> 3;
  const int e_start = p * psz;
  const int e_end = min(ne, e_start + psz);
  const int rowbase = rg * 128 + wv * 32;
  const u64 gm = 0xFFFFull << (q * 16);
  const u64 lanelow = (lane == 63) ? 0x7FFFFFFFFFFFFFFFull
                                   : ((1ull << (lane + 1)) - 1) >> 1;

  #pragma unroll
  for (int j = 0; j < 8; ++j) {
    int idx = lane + 64 * j; int rw = idx >> 4, sl = idx & 15;
    Slot[wv][rw][sl] = (0xFF800000ull << 32) | 0x7FFFFFFFull;  // (-inf, MAX)
  }
  if (lane < 16) Qn[wv][lane] = 0;
  if (lane < 32) Sth[wv][lane] = -INF_F;
  float mnv0 = -INF_F, mnv1 = -INF_F;   // owner-lane min cache (rows lane, 16+lane)
  int   mns0 = 0, mns1 = 0;

  // A fragments resident in registers: 2 rowfrags x 8 ksteps x 8 bf16
  bf16x8 a0[8], a1[8];
  #pragma unroll
  for (int s = 0; s < 8; ++s) {
    a0[s] = *(const bf16x8*)(spanbf + (size_t)(rowbase + m) * 256 + s * 32 + q * 8);
    a1[s] = *(const bf16x8*)(spanbf + (size_t)(rowbase + 16 + m) * 256 + s * 32 + q * 8);
  }

  const int ntiles = (e_end - e_start + 63) >> 6;
  for (int tile = 0; tile < ntiles; ++tile) {
    const int eb = e_start + (tile << 6);
    __syncthreads();
    #pragma unroll
    for (int i = 0; i < 8; ++i) {
      int id = t + 256 * i; int e = id >> 5, qq = id & 31;
      uint4 v = make_uint4(0u, 0u, 0u, 0u);
      int ge = eb + e;
      if (ge < e_end) v = *(const uint4*)((const char*)entbf + (size_t)ge * 512 + qq * 16);
      *(uint4*)((char*)Elds + (((e << 5) | (qq ^ (e & 31))) << 4)) = v;
    }
    __syncthreads();

    // refresh producer threshold caches (stale within a tile: harmless)
    float th0[4], th1[4];
    #pragma unroll
    for (int r = 0; r < 4; ++r) {
      th0[r] = Sth[wv][q4 + r];
      th1[r] = Sth[wv][16 + q4 + r];
    }

    for (int c = 0; c < 4; ++c) {
      f32x4 acc0 = {0.f, 0.f, 0.f, 0.f}, acc1 = {0.f, 0.f, 0.f, 0.f};
      const int el = c * 16 + m, sw = el & 31, bc = el << 5;
      #pragma unroll
      for (int s = 0; s < 8; ++s) {
        int qq = s * 4 + q;
        bf16x8 bfr = *(const bf16x8*)((const char*)Elds + ((bc | (qq ^ sw)) << 4));
        acc0 = __builtin_amdgcn_mfma_f32_16x16x32_bf16(a0[s], bfr, acc0, 0, 0, 0);
        acc1 = __builtin_amdgcn_mfma_f32_16x16x32_bf16(a1[s], bfr, acc1, 0, 0, 0);
      }
      const int gent = eb + c * 16 + m;
      const bool valid = gent < e_end;

      auto produce = [&](const f32x4& av, const float* th) {
        #pragma unroll
        for (int r = 0; r < 4; ++r) {
          bool hr = valid && (av[r] > th[r]);
          u64 mr = __ballot(hr) & gm;
          if (hr) {
            int rq = q4 + r;
            int pos = (int)__popcll(mr & lanelow);
            Q[wv][rq][pos] = ((u64)__float_as_uint(av[r]) << 32) | (u32)gent;
            if (pos == 0) Qn[wv][rq] = (u32)__popcll(mr);
          }
        }
      };
      auto drain = [&](int half, float& mnv, int& mns) {
        __builtin_amdgcn_sched_barrier(0);
        if (lane < 16) {
          int cnt = (int)Qn[wv][lane];
          if (cnt > 0) {
            int rw = half * 16 + lane;
            for (int i = 0; i < cnt; ++i) {
              u64 e = Q[wv][lane][i];
              float v = __uint_as_float((u32)(e >> 32));
              if (v > mnv) {
                Slot[wv][rw][mns] = e;
                float mv = INF_F; int ms2 = 0;
                #pragma unroll
                for (int s2 = 0; s2 < 16; ++s2) {
                  u64 sv = Slot[wv][rw][s2];
                  float f = __uint_as_float((u32)(sv >> 32));
                  if (f < mv) { mv = f; ms2 = s2; }
                }
                mnv = mv; mns = ms2;
              }
            }
            Qn[wv][lane] = 0;
            Sth[wv][rw] = mnv;
          }
        }
        __builtin_amdgcn_sched_barrier(0);
      };

      produce(acc0, th0);
      drain(0, mnv0, mns0);
      produce(acc1, th1);
      drain(1, mnv1, mns1);
    }
  }

  if (lane < 16) {
    #pragma unroll
    for (int h = 0; h < 2; ++h) {
      int rw = h * 16 + lane;
      int row = rowbase + rw;
      for (int s = 0; s < 16; ++s) {
        u64 e = Slot[wv][rw][s];
        Rpv[(size_t)row * 128 + p * 16 + s] = __uint_as_float((u32)(e >> 32));
        Rpi[(size_t)row * 128 + p * 16 + s] = (int)(u32)e;
      }
    }
  }
}

// ---------------------------------------------------------------------------
// K2b: exact top-16 of the 128 partition candidates per row (rank counting).
// grid = 2048 blocks x 4 waves (1 row/wave).
// ---------------------------------------------------------------------------
__global__ __launch_bounds__(256) void k2_merge(
    const float* __restrict__ Rpv, const int* __restrict__ Rpi,
    int* __restrict__ Ridx) {
  const int t = threadIdx.x, lane = t & 63, wv = t >> 6;
  const int row = blockIdx.x * 4 + wv;
  const float va = Rpv[(size_t)row * 128 + lane];
  const int   ea = Rpi[(size_t)row * 128 + lane];
  const float vb = Rpv[(size_t)row * 128 + 64 + lane];
  const int   eb = Rpi[(size_t)row * 128 + 64 + lane];
  int ca = 0, cb = 0;
  for (int i = 0; i < 64; ++i) {
    float ov = __shfl(va, i); int oi = __shfl(ea, i);
    ca += (ov > va || (ov == va && oi < ea));
    cb += (ov > vb || (ov == vb && oi < eb));
  }
  for (int i = 0; i < 64; ++i) {
    float ov = __shfl(vb, i); int oi = __shfl(eb, i);
    ca += (ov > va || (ov == va && oi < ea));
    cb += (ov > vb || (ov == vb && oi < eb));
  }
  if (ca < 16) Ridx[(size_t)row * 16 + ca] = ea;
  if (cb < 16) Ridx[(size_t)row * 16 + cb] = eb;
}

// ---------------------------------------------------------------------------
// K3: recompute span row fp64, exact re-rank of 16 candidates -> ordered
// top-8, then 2-layer star-GCN (fp32). grid = 8192 blocks, 256 threads.
// ---------------------------------------------------------------------------
__global__ __launch_bounds__(256) void k3_gcn(
    const float* __restrict__ emb, const float* __restrict__ Wsp,
    const float* __restrict__ bsp, const float* __restrict__ ent,
    const int* __restrict__ Ridx,
    const float* __restrict__ W1, const float* __restrict__ b1,
    const float* __restrict__ W2, const float* __restrict__ b2,
    float* __restrict__ out2, int ne) {
  __shared__ float  SMx[256];
  __shared__ float  CLS[256];
  __shared__ double SPN[256];
  __shared__ float  Xc[16][256];
  __shared__ float  Mm[8][256];
  __shared__ double dpart[16][16];
  __shared__ double dval[16];
  __shared__ int    cidx[16];
  __shared__ int    order[8];
  const int n = blockIdx.x;
  const int t = threadIdx.x;
  const int w = n >> 10, b = (n >> 8) & 3, s = n & 255;
  const float* eb = emb + (size_t)b * 65536;

  CLS[t] = eb[t];
  float m = eb[s * 256 + t];
  for (int j = 1; j <= w; ++j)
    if (s + j < 256) m = fmaxf(m, eb[(s + j) * 256 + t]);
  SMx[t] = m;
  if (t < 16) {
    int c = Ridx[(size_t)n * 16 + t];
    if ((unsigned)c >= (unsigned)ne) c = 0;   // defensive
    cidx[t] = c;
  }
  __syncthreads();

  double a = (double)bsp[t];
  for (int k = 0; k < 256; k += 4) {
    a += (double)SMx[k + 0] * (double)Wsp[(size_t)(k + 0) * 256 + t];
    a += (double)SMx[k + 1] * (double)Wsp[(size_t)(k + 1) * 256 + t];
    a += (double)SMx[k + 2] * (double)Wsp[(size_t)(k + 2) * 256 + t];
    a += (double)SMx[k + 3] * (double)Wsp[(size_t)(k + 3) * 256 + t];
  }
  for (int k = 0; k < 256; k += 4) {
    a += (double)CLS[k + 0] * (double)Wsp[(size_t)(256 + k + 0) * 256 + t];
    a += (double)CLS[k + 1] * (double)Wsp[(size_t)(256 + k + 1) * 256 + t];
    a += (double)CLS[k + 2] * (double)Wsp[(size_t)(256 + k + 2) * 256 + t];
    a += (double)CLS[k + 3] * (double)Wsp[(size_t)(256 + k + 3) * 256 + t];
  }
  a += (double)(w + 1) * (double)Wsp[(size_t)512 * 256 + t];
  SPN[t] = a;
  __syncthreads();

  const int jr = t >> 4;
  const int kb = (t & 15) * 16;
  float x[16];
  {
    const float4* src = (const float4*)(ent + (size_t)cidx[jr] * 256 + kb);
    float4 v0 = src[0], v1 = src[1], v2 = src[2], v3 = src[3];
    x[0]=v0.x; x[1]=v0.y; x[2]=v0.z; x[3]=v0.w;
    x[4]=v1.x; x[5]=v1.y; x[6]=v1.z; x[7]=v1.w;
    x[8]=v2.x; x[9]=v2.y; x[10]=v2.z; x[11]=v2.w;
    x[12]=v3.x; x[13]=v3.y; x[14]=v3.z; x[15]=v3.w;
    #pragma unroll
    for (int qq = 0; qq < 16; ++qq) Xc[jr][kb + qq] = x[qq];
  }
  double pp = 0.0;
  #pragma unroll
  for (int kk = 0; kk < 16; ++kk) pp += (double)x[kk] * SPN[kb + kk];
  dpart[jr][t & 15] = pp;
  __syncthreads();
  if (t < 16) {
    double sacc = 0.0;
    for (int qq = 0; qq < 16; ++qq) sacc += dpart[t][qq];
    dval[t] = sacc;
  }
  __syncthreads();
  if (t == 0) {
    unsigned used = 0;
    for (int o = 0; o < 8; ++o) {
      int best = -1; double bv = 0.0; int bi = 0;
      for (int j = 0; j < 16; ++j) {
        if (used & (1u << j)) continue;
        if (best < 0 || dval[j] > bv || (dval[j] == bv && cidx[j] < bi)) {
          best = j; bv = dval[j]; bi = cidx[j];
        }
      }
      used |= (1u << best);
      order[o] = best;
    }
  }
  __syncthreads();

  {
    float x0 = Xc[order[0]][t];
    float xs[7]; float ssum = 0.f;
    #pragma unroll
    for (int j = 1; j < 8; ++j) { xs[j - 1] = Xc[order[j]][t]; ssum += xs[j - 1]; }
    Mm[0][t] = x0 * 0.125f + ssum * 0.25f;
    #pragma unroll
    for (int j = 1; j < 8; ++j) Mm[j][t] = x0 * 0.25f + xs[j - 1] * 0.5f;
  }
  __syncthreads();

  float acc[8];
  {
    float bbv = b1[t];
    #pragma unroll
    for (int r = 0; r < 8; ++r) acc[r] = bbv;
    for (int k = 0; k < 256; k += 4) {
      float w0 = W1[(size_t)(k + 0) * 256 + t];
      float w1 = W1[(size_t)(k + 1) * 256 + t];
      float w2 = W1[(size_t)(k + 2) * 256 + t];
      float w3 = W1[(size_t)(k + 3) * 256 + t];
      #pragma unroll
      for (int r = 0; r < 8; ++r) {
        float4 mq = *(const float4*)&Mm[r][k];
        acc[r] += mq.x * w0; acc[r] += mq.y * w1;
        acc[r] += mq.z * w2; acc[r] += mq.w * w3;
      }
    }
  }
  #pragma unroll
  for (int r = 0; r < 8; ++r) Xc[r][t] = fmaxf(acc[r], 0.f);
  __syncthreads();

  {
    float y0 = Xc[0][t];
    float ys[7]; float ss = 0.f;
    #pragma unroll
    for (int j = 1; j < 8; ++j) { ys[j - 1] = Xc[j][t]; ss += ys[j - 1]; }
    float m0 = y0 * 0.125f + ss * 0.25f;
    float mj[7];
    #pragma unroll
    for (int j = 1; j < 8; ++j) mj[j - 1] = y0 * 0.25f + ys[j - 1] * 0.5f;
    Mm[0][t] = m0;
    #pragma unroll
    for (int j = 1; j < 8; ++j) Mm[j][t] = mj[j - 1];
  }
  __syncthreads();

  {
    float bbv = b2[t];
    #pragma unroll
    for (int r = 0; r < 8; ++r) acc[r] = bbv;
    for (int k = 0; k < 256; k += 4) {
      float w0 = W2[(size_t)(k + 0) * 256 + t];
      float w1 = W2[(size_t)(k + 1) * 256 + t];
      float w2 = W2[(size_t)(k + 2) * 256 + t];
      float w3 = W2[(size_t)(k + 3) * 256 + t];
      #pragma unroll
      for (int r = 0; r < 8; ++r) {
        float4 mq = *(const float4*)&Mm[r][k];
        acc[r] += mq.x * w0; acc[r] += mq.y * w1;
        acc[r] += mq.z * w2; acc[r] += mq.w * w3;
      }
    }
  }
  float* ob = out2 + (size_t)n * 2048 + t;
  #pragma unroll
  for (int r = 0; r < 8; ++r) ob[(size_t)r * 256] = acc[r];
}

// ---------------------------------------------------------------------------
extern "C" void kernel_launch(void* const* d_in, const int* in_sizes, int n_in,
                              void* d_out, int out_size, void* d_ws, size_t ws_size,
                              hipStream_t stream) {
  const float* emb = (const float*)d_in[0];
  const float* ent = (const float*)d_in[1];
  const float* Wsp = (const float*)d_in[2];
  const float* bsp = (const float*)d_in[3];
  const float* W1  = (const float*)d_in[4];
  const float* b1  = (const float*)d_in[5];
  const float* W2  = (const float*)d_in[6];
  const float* b2  = (const float*)d_in[7];
  const int ne = in_sizes[1] / 256;   // 50000

  float* out  = (float*)d_out;
  float* out0 = out;                        // cls: 1024
  float* out1 = out + 1024;                 // span_repr: 8192*256
  float* out2 = out + 1024 + 2097152;       // subgraph_out: 64 MB region

  // scratch overlays on out2 (consumed before k3 overwrites; strict order):
  char* ov = (char*)out2;
  u16*   entbf  = (u16*)(ov);                     // 25.6 MB bf16 entity table
  u16*   spanbf = (u16*)(ov + 33554432);          //  4 MB bf16 span matrix
  float* Rpv    = (float*)(ov + 41943040);        //  4 MB partial topk vals
  int*   Rpi    = (int*)  (ov + 50331648);        //  4 MB partial topk idx
  int*   Ridx   = (int*)d_ws;                     // 512 KB final top-16 idx

  hipLaunchKernelGGL(k0_cvt, dim3((ne * 64 + 255) / 256), dim3(256), 0, stream,
                     ent, entbf, ne * 64);
  hipLaunchKernelGGL(k1_span, dim3(1024), dim3(256), 0, stream,
                     emb, Wsp, bsp, out0, out1, spanbf);
  hipLaunchKernelGGL(k2_mfma, dim3(512), dim3(256), 0, stream,
                     spanbf, entbf, ne, Rpv, Rpi);
  hipLaunchKernelGGL(k2_merge, dim3(2048), dim3(256), 0, stream,
                     Rpv, Rpi, Ridx);
  hipLaunchKernelGGL(k3_gcn, dim3(8192), dim3(256), 0, stream,
                     emb, Wsp, bsp, ent, Ridx, W1, b1, W2, b2, out2, ne);
}